// Round 9
// baseline (169.339 us; speedup 1.0000x reference)
//
#include <hip/hip_runtime.h>
#include <math.h>

typedef unsigned int uint;
typedef unsigned short ushort;
typedef __attribute__((ext_vector_type(8))) short bf16x8;
typedef __attribute__((ext_vector_type(16))) float f32x16;

static constexpr int Mdim = 4096;
static constexpr int Ndim = 4096;
static constexpr int Kdim = 4096;
static constexpr int Hdim = 4096;

// ---------------- numerics helpers ----------------

__device__ __forceinline__ float fp8_round(float v) {
  float a = fabsf(v);
  float q;
  if (a >= 0x1p-6f) {           // normal range: quantum 2^(e-3)
    uint u = __float_as_uint(a);
    int e = (int)(u >> 23) - 127;
    float quant = __uint_as_float((uint)(e - 3 + 127) << 23);
    q = rintf(a / quant) * quant;
    q = fminf(q, 448.f);
  } else {                      // subnormal: quantum 2^-9
    q = rintf(a * 512.f) * 0x1p-9f;
  }
  return copysignf(q, v);
}

__device__ __forceinline__ float e2m1_round(float t) {
  float a = fabsf(t);
  float q;
  if (a <= 0.25f) q = 0.f;
  else if (a <= 0.75f) q = 0.5f;
  else if (a <= 1.25f) q = 1.f;
  else if (a <= 1.75f) q = 1.5f;
  else if (a <= 2.5f)  q = 2.f;
  else if (a <= 3.5f)  q = 3.f;
  else if (a <= 5.f)   q = 4.f;
  else                 q = 6.f;
  return copysignf(q, t);
}

__device__ __forceinline__ float e2m1_decode(uint c) {
  uint m = c & 7u;
  float v;
  if (m == 0u) v = 0.f;
  else if (m == 1u) v = 0.5f;
  else v = __uint_as_float(((126u + (m >> 1)) << 23) | ((m & 1u) << 22));
  return (c & 8u) ? -v : v;
}

// ---------------- merged prep kernel (unchanged from round 8) ----------------

__global__ void prep_kernel(const float* __restrict__ x, const int* __restrict__ w,
                            const float* __restrict__ wscale,
                            const float* __restrict__ scalep,
                            ushort* __restrict__ a_deq, ushort* __restrict__ b_deq) {
  const int b = blockIdx.x;
  if (b < Mdim) {
    const int row = b;
    const int blk = threadIdx.x;
    const float gs = 1.0f / scalep[0];
    const float c6 = gs / 6.0f;
    const float* gp = x + (size_t)row * (2 * Hdim) + blk * 16;
    const float* up = gp + Hdim;
    float y[16];
    float amax = 0.f;
#pragma unroll
    for (int i = 0; i < 4; ++i) {
      float4 gv = ((const float4*)gp)[i];
      float4 uv = ((const float4*)up)[i];
      float ga[4] = {gv.x, gv.y, gv.z, gv.w};
      float ua[4] = {uv.x, uv.y, uv.z, uv.w};
#pragma unroll
      for (int j = 0; j < 4; ++j) {
        float xv = ga[j];
        float sig = 1.0f / (1.0f + expf(-xv));
        float yy = xv * sig * ua[j];
        y[i * 4 + j] = yy;
        amax = fmaxf(amax, fabsf(yy));
      }
    }
    const float sf = fp8_round(amax * c6);
    uint outp[8];
    if (sf > 0.f) {
      const float inv = gs / sf;
#pragma unroll
      for (int i = 0; i < 8; ++i) {
        float t0 = fminf(fmaxf(y[2 * i] * inv, -6.f), 6.f);
        float t1 = fminf(fmaxf(y[2 * i + 1] * inv, -6.f), 6.f);
        float d0 = e2m1_round(t0) * sf;
        float d1 = e2m1_round(t1) * sf;
        outp[i] = (__float_as_uint(d0) >> 16) | ((__float_as_uint(d1) >> 16) << 16);
      }
    } else {
#pragma unroll
      for (int i = 0; i < 8; ++i) outp[i] = 0u;
    }
    uint4* dst = (uint4*)(a_deq + (size_t)row * Hdim + blk * 16);
    dst[0] = (uint4){outp[0], outp[1], outp[2], outp[3]};
    dst[1] = (uint4){outp[4], outp[5], outp[6], outp[7]};
  } else {
    const int n = b - Mdim;
    const int blk = threadIdx.x;
    const int4* wp = (const int4*)(w + (size_t)n * (Hdim / 2) + blk * 8);
    int4 w0 = wp[0], w1 = wp[1];
    int wb[8] = {w0.x, w0.y, w0.z, w0.w, w1.x, w1.y, w1.z, w1.w};
    const float ws = fp8_round(wscale[(size_t)n * (Hdim / 16) + blk]);
    uint outp[8];
#pragma unroll
    for (int i = 0; i < 8; ++i) {
      uint byte = (uint)wb[i] & 0xFFu;
      float vlo = e2m1_decode(byte & 15u) * ws;
      float vhi = e2m1_decode(byte >> 4) * ws;
      outp[i] = (__float_as_uint(vlo) >> 16) | ((__float_as_uint(vhi) >> 16) << 16);
    }
    uint4* dst = (uint4*)(b_deq + (size_t)n * Hdim + blk * 16);
    dst[0] = (uint4){outp[0], outp[1], outp[2], outp[3]};
    dst[1] = (uint4){outp[4], outp[5], outp[6], outp[7]};
  }
}

// ---------------- kernel 3: 256x256 bf16 GEMM, 32x32x16 MFMA + 1 barrier/phase ----------------
// R3 dataflow (pipelined ds_reads one phase ahead, triple-buffered A, B dbuf,
// vmcnt(6) checkpoint at ph2) with: (a) mfma_f32_32x32x16_bf16 (higher ceiling,
// half the MFMA instructions), (b) single barrier per phase (4/K-tile).
// Per wave: 128x64 output = 4 m-tiles x 2 n-tiles of 32x32; per K-tile 4 ksteps.
// A/B operand layout: lane reads row (lane&31), k=(lane>>5)*8+j.
// C/D layout: col=lane&31, row=(reg&3)+8*(reg>>2)+4*(lane>>5)  [m74/m101].
// Phases: ph0 {read af1(mt1); stage A(kt+2)h0; MFMA mt0; BAR}; ph1 {af2; A h1;
// MFMA mt1; BAR}; ph2 {af3; B(kt+2)h0; MFMA mt2; vmcnt(6); BAR}; ph3 {B h1;
// MFMA mt3; read af0'+bfr' (next tile, from pA1/pB1); BAR}.

#define BM 256
#define BN 256
#define BK 64
#define NT (Kdim / BK)
#define TILE_E (256 * 64)     // 16384 ushort = 32 KB

__device__ __forceinline__ void gload_lds16(const ushort* g, ushort* l) {
  __builtin_amdgcn_global_load_lds((const __attribute__((address_space(1))) void*)g,
                                   (__attribute__((address_space(3))) void*)l,
                                   16, 0, 0);
}

#define BAR()                                   \
  do {                                          \
    asm volatile("" ::: "memory");              \
    __builtin_amdgcn_s_barrier();               \
    asm volatile("" ::: "memory");              \
  } while (0)

__global__ __launch_bounds__(512, 2) void gemm256(const ushort* __restrict__ A,
                                                  const ushort* __restrict__ B,
                                                  float* __restrict__ C,
                                                  const float* __restrict__ scalep,
                                                  const float* __restrict__ wscale2p) {
  extern __shared__ __align__(16) ushort lds[];   // 163840 B
  const int tid = threadIdx.x;
  const int wave = tid >> 6;
  const int lane = tid & 63;
  const int wm = wave >> 2;        // 0..1 -> 128 C-rows
  const int wn = wave & 3;         // 0..3 -> 64 C-cols
  const int lr = lane & 31;        // row-in-tile (A) / col-in-tile (B)
  const int lh = lane >> 5;        // k-half selector

  const int wg = blockIdx.x;
  const int swz = (wg & 7) * 32 + (wg >> 3);      // 256 % 8 == 0 -> bijective
  const int m0 = (swz >> 4) * BM;
  const int n0 = (swz & 15) * BN;

  f32x16 acc[4][2];
#pragma unroll
  for (int mt = 0; mt < 4; ++mt)
#pragma unroll
    for (int nt = 0; nt < 2; ++nt)
#pragma unroll
      for (int r = 0; r < 16; ++r) acc[mt][nt][r] = 0.f;

  // rotating LDS slot pointers
  ushort* pA0 = lds;                  // A read slot (tile kt)
  ushort* pA1 = lds + TILE_E;         // A tile kt+1
  ushort* pA2 = lds + 2 * TILE_E;     // A stage target (tile kt+2)
  ushort* pB0 = lds + 3 * TILE_E;     // B read slot (tile kt)
  ushort* pB1 = lds + 4 * TILE_E;     // B tile kt+1

  // staging geometry (unchanged): row = h*128 + rr*64 + wave*8 + lane/8;
  // global source chunk pre-swizzled (c ^ (row&7)) -> LDS[row][p] = chunk p^(row&7).
  int goffA[4], goffB[4], loff[4];
#pragma unroll
  for (int h = 0; h < 2; ++h)
#pragma unroll
    for (int rr = 0; rr < 2; ++rr) {
      const int idx = h * 2 + rr;
      const int rowb = h * 128 + rr * 64 + wave * 8;
      const int trow = rowb + (lane >> 3);
      const int sc = (lane & 7) ^ (trow & 7);
      goffA[idx] = (m0 + trow) * Kdim + sc * 8;
      goffB[idx] = (n0 + trow) * Kdim + sc * 8;
      loff[idx] = rowb * 64;
    }

#define STAGE_A(h, kcol)                                                       \
  do {                                                                         \
    gload_lds16(A + (size_t)goffA[(h)*2 + 0] + (kcol), pA2 + loff[(h)*2 + 0]); \
    gload_lds16(A + (size_t)goffA[(h)*2 + 1] + (kcol), pA2 + loff[(h)*2 + 1]); \
  } while (0)
#define STAGE_B(h, kcol)                                                       \
  do {                                                                         \
    gload_lds16(B + (size_t)goffB[(h)*2 + 0] + (kcol), pB0 + loff[(h)*2 + 0]); \
    gload_lds16(B + (size_t)goffB[(h)*2 + 1] + (kcol), pB0 + loff[(h)*2 + 1]); \
  } while (0)

  // fragment read geometry: element offset = row*64 + ((c ^ (row&7))*8),
  // row&7 == lr&7 (tile bases are multiples of 32). c = 2*s + lh.
  const int laneA = (wm * 128 + lr) * 64;
  const int laneB = (wn * 64 + lr) * 64;
  int xk[4];
#pragma unroll
  for (int s = 0; s < 4; ++s) xk[s] = ((2 * s + lh) ^ (lr & 7)) * 8;

#define RD_A(dst, base, mt)                                                \
  do {                                                                     \
    _Pragma("unroll")                                                      \
    for (int s = 0; s < 4; ++s)                                            \
      dst[s] = *(const bf16x8*)((base) + (mt) * 2048 + xk[s]);             \
  } while (0)
#define RD_B(dst, base)                                                    \
  do {                                                                     \
    _Pragma("unroll")                                                      \
    for (int nt = 0; nt < 2; ++nt)                                         \
      _Pragma("unroll")                                                    \
      for (int s = 0; s < 4; ++s)                                          \
        dst[nt][s] = *(const bf16x8*)((base) + nt * 2048 + xk[s]);         \
  } while (0)

#define MFMA_T(mt, AF)                                                         \
  do {                                                                         \
    __builtin_amdgcn_s_setprio(1);                                             \
    _Pragma("unroll")                                                          \
    for (int s = 0; s < 4; ++s) {                                              \
      acc[mt][0] = __builtin_amdgcn_mfma_f32_32x32x16_bf16(AF[s], bfr[0][s],   \
                                                           acc[mt][0], 0, 0, 0); \
      acc[mt][1] = __builtin_amdgcn_mfma_f32_32x32x16_bf16(AF[s], bfr[1][s],   \
                                                           acc[mt][1], 0, 0, 0); \
    }                                                                          \
    __builtin_amdgcn_s_setprio(0);                                             \
  } while (0)

  // ---- prologue: stage A0,B0 (->slot0), A1 (->slot1), B1 (->Bslot1) ----
  {
    ushort* sv = pA2;
    pA2 = pA0; STAGE_A(0, 0); STAGE_A(1, 0);
    STAGE_B(0, 0); STAGE_B(1, 0);
    pA2 = pA1; STAGE_A(0, BK); STAGE_A(1, BK);
    { ushort* t = pB0; pB0 = pB1; STAGE_B(0, BK); STAGE_B(1, BK); pB0 = t; }
    pA2 = sv;
  }
  asm volatile("s_waitcnt vmcnt(8)" ::: "memory");   // tile0 landed; tile1 in flight
  BAR();

  bf16x8 af0[4], af1[4], af2[4], af3[4], bfr[2][4];
  RD_A(af0, pA0 + laneA, 0);
  RD_B(bfr, pB0 + laneB);

  for (int kt = 0; kt < NT; ++kt) {
    const int kc = (kt + 2) * BK;
    const bool stg = (kt + 2) < NT;
    const bool nxt = (kt + 1) < NT;
    const ushort* aB = pA0 + laneA;

    // ---- ph0: read af1 (mt1); stage A(kt+2)h0; MFMA mt0 ----
    RD_A(af1, aB, 1);
    if (stg) STAGE_A(0, kc);
    MFMA_T(0, af0);
    BAR();

    // ---- ph1: read af2; stage A(kt+2)h1; MFMA mt1 ----
    RD_A(af2, aB, 2);
    if (stg) STAGE_A(1, kc);
    MFMA_T(1, af1);
    BAR();

    // ---- ph2: read af3; stage B(kt+2)h0; MFMA mt2; vmcnt checkpoint ----
    RD_A(af3, aB, 3);
    if (stg) STAGE_B(0, kc);
    MFMA_T(2, af2);
    if (stg) asm volatile("s_waitcnt vmcnt(6)" ::: "memory");  // A(kt+1),B(kt+1) landed
    else     asm volatile("s_waitcnt vmcnt(0)" ::: "memory");
    BAR();

    // ---- ph3: stage B(kt+2)h1; MFMA mt3; read next tile's af0+bfr ----
    if (stg) STAGE_B(1, kc);
    MFMA_T(3, af3);
    if (nxt) {
      RD_A(af0, pA1 + laneA, 0);
      RD_B(bfr, pB1 + laneB);
    }
    BAR();

    // rotate slots: A three-way, B swap
    { ushort* t = pA0; pA0 = pA1; pA1 = pA2; pA2 = t; }
    { ushort* t = pB0; pB0 = pB1; pB1 = t; }
  }

  const float alpha = scalep[0] * wscale2p[0];
#pragma unroll
  for (int mt = 0; mt < 4; ++mt)
#pragma unroll
    for (int nt = 0; nt < 2; ++nt) {
      const int col = n0 + wn * 64 + nt * 32 + lr;
      const int rbase = m0 + wm * 128 + mt * 32 + 4 * lh;
#pragma unroll
      for (int r = 0; r < 16; ++r) {
        const int row = rbase + (r & 3) + 8 * (r >> 2);
        C[(size_t)row * Ndim + col] = alpha * acc[mt][nt][r];
      }
    }
}

// ---------------- launcher ----------------

extern "C" void kernel_launch(void* const* d_in, const int* in_sizes, int n_in,
                              void* d_out, int out_size, void* d_ws, size_t ws_size,
                              hipStream_t stream) {
  const float* x       = (const float*)d_in[0];
  const int*   w       = (const int*)d_in[1];
  const float* wscale  = (const float*)d_in[2];
  const float* wscale2 = (const float*)d_in[3];
  const float* scale   = (const float*)d_in[4];
  float* out = (float*)d_out;

  ushort* a_deq = (ushort*)d_ws;                       // 32 MB
  ushort* b_deq = a_deq + (size_t)Mdim * Kdim;         // 32 MB

  prep_kernel<<<Mdim + Ndim, 256, 0, stream>>>(x, w, wscale, scale, a_deq, b_deq);

  (void)hipFuncSetAttribute((const void*)gemm256, hipFuncAttributeMaxDynamicSharedMemorySize, 163840);
  gemm256<<<(Mdim / BM) * (Ndim / BN), 512, 163840, stream>>>(a_deq, b_deq, out, scale, wscale2);
}

// Round 10
// 159.862 us; speedup vs baseline: 1.0593x; 1.0593x over previous
//
#include <hip/hip_runtime.h>
#include <math.h>

typedef unsigned int uint;
typedef unsigned short ushort;
typedef __attribute__((ext_vector_type(8))) short bf16x8;
typedef __attribute__((ext_vector_type(16))) float f32x16;

static constexpr int Mdim = 4096;
static constexpr int Ndim = 4096;
static constexpr int Kdim = 4096;
static constexpr int Hdim = 4096;

// ---------------- numerics helpers ----------------

__device__ __forceinline__ float fp8_round(float v) {
  float a = fabsf(v);
  float q;
  if (a >= 0x1p-6f) {           // normal range: quantum 2^(e-3)
    uint u = __float_as_uint(a);
    int e = (int)(u >> 23) - 127;
    float quant = __uint_as_float((uint)(e - 3 + 127) << 23);
    q = rintf(a / quant) * quant;
    q = fminf(q, 448.f);
  } else {                      // subnormal: quantum 2^-9
    q = rintf(a * 512.f) * 0x1p-9f;
  }
  return copysignf(q, v);
}

__device__ __forceinline__ float e2m1_round(float t) {
  float a = fabsf(t);
  float q;
  if (a <= 0.25f) q = 0.f;
  else if (a <= 0.75f) q = 0.5f;
  else if (a <= 1.25f) q = 1.f;
  else if (a <= 1.75f) q = 1.5f;
  else if (a <= 2.5f)  q = 2.f;
  else if (a <= 3.5f)  q = 3.f;
  else if (a <= 5.f)   q = 4.f;
  else                 q = 6.f;
  return copysignf(q, t);
}

__device__ __forceinline__ float e2m1_decode(uint c) {
  uint m = c & 7u;
  float v;
  if (m == 0u) v = 0.f;
  else if (m == 1u) v = 0.5f;
  else v = __uint_as_float(((126u + (m >> 1)) << 23) | ((m & 1u) << 22));
  return (c & 8u) ? -v : v;
}

// ---------------- merged prep kernel (unchanged, at HBM roofline) ----------------

__global__ void prep_kernel(const float* __restrict__ x, const int* __restrict__ w,
                            const float* __restrict__ wscale,
                            const float* __restrict__ scalep,
                            ushort* __restrict__ a_deq, ushort* __restrict__ b_deq) {
  const int b = blockIdx.x;
  if (b < Mdim) {
    const int row = b;
    const int blk = threadIdx.x;
    const float gs = 1.0f / scalep[0];
    const float c6 = gs / 6.0f;
    const float* gp = x + (size_t)row * (2 * Hdim) + blk * 16;
    const float* up = gp + Hdim;
    float y[16];
    float amax = 0.f;
#pragma unroll
    for (int i = 0; i < 4; ++i) {
      float4 gv = ((const float4*)gp)[i];
      float4 uv = ((const float4*)up)[i];
      float ga[4] = {gv.x, gv.y, gv.z, gv.w};
      float ua[4] = {uv.x, uv.y, uv.z, uv.w};
#pragma unroll
      for (int j = 0; j < 4; ++j) {
        float xv = ga[j];
        float sig = 1.0f / (1.0f + expf(-xv));
        float yy = xv * sig * ua[j];
        y[i * 4 + j] = yy;
        amax = fmaxf(amax, fabsf(yy));
      }
    }
    const float sf = fp8_round(amax * c6);
    uint outp[8];
    if (sf > 0.f) {
      const float inv = gs / sf;
#pragma unroll
      for (int i = 0; i < 8; ++i) {
        float t0 = fminf(fmaxf(y[2 * i] * inv, -6.f), 6.f);
        float t1 = fminf(fmaxf(y[2 * i + 1] * inv, -6.f), 6.f);
        float d0 = e2m1_round(t0) * sf;
        float d1 = e2m1_round(t1) * sf;
        outp[i] = (__float_as_uint(d0) >> 16) | ((__float_as_uint(d1) >> 16) << 16);
      }
    } else {
#pragma unroll
      for (int i = 0; i < 8; ++i) outp[i] = 0u;
    }
    uint4* dst = (uint4*)(a_deq + (size_t)row * Hdim + blk * 16);
    dst[0] = (uint4){outp[0], outp[1], outp[2], outp[3]};
    dst[1] = (uint4){outp[4], outp[5], outp[6], outp[7]};
  } else {
    const int n = b - Mdim;
    const int blk = threadIdx.x;
    const int4* wp = (const int4*)(w + (size_t)n * (Hdim / 2) + blk * 8);
    int4 w0 = wp[0], w1 = wp[1];
    int wb[8] = {w0.x, w0.y, w0.z, w0.w, w1.x, w1.y, w1.z, w1.w};
    const float ws = fp8_round(wscale[(size_t)n * (Hdim / 16) + blk]);
    uint outp[8];
#pragma unroll
    for (int i = 0; i < 8; ++i) {
      uint byte = (uint)wb[i] & 0xFFu;
      float vlo = e2m1_decode(byte & 15u) * ws;
      float vhi = e2m1_decode(byte >> 4) * ws;
      outp[i] = (__float_as_uint(vlo) >> 16) | ((__float_as_uint(vhi) >> 16) << 16);
    }
    uint4* dst = (uint4*)(b_deq + (size_t)n * Hdim + blk * 16);
    dst[0] = (uint4){outp[0], outp[1], outp[2], outp[3]};
    dst[1] = (uint4){outp[4], outp[5], outp[6], outp[7]};
  }
}

// ---------------- kernel 3: 256x256 bf16 GEMM ----------------
// EXACT R3/R8 schedule (pipelined ds_reads one phase ahead, triple-buffered A,
// B double-buffer, TWO barriers per phase, vmcnt(6)@ph2, compiler-scheduled,
// no sched pins) with ONLY the MFMA shape changed: mfma_f32_32x32x16_bf16.
// Per wave: 128x64 out = 4 m-tiles x 2 n-tiles of 32x32; 4 ksteps per K-tile.
// A/B operand: lane reads row (lane&31), k-half (lane>>5). C/D: col=lane&31,
// row=(reg&3)+8*(reg>>2)+4*(lane>>5)  [m74/m101; validated in round 9's pass].

#define BM 256
#define BN 256
#define BK 64
#define NT (Kdim / BK)
#define TILE_E (256 * 64)     // 16384 ushort = 32 KB

__device__ __forceinline__ void gload_lds16(const ushort* g, ushort* l) {
  __builtin_amdgcn_global_load_lds((const __attribute__((address_space(1))) void*)g,
                                   (__attribute__((address_space(3))) void*)l,
                                   16, 0, 0);
}

#define BAR()                                   \
  do {                                          \
    asm volatile("" ::: "memory");              \
    __builtin_amdgcn_s_barrier();               \
    asm volatile("" ::: "memory");              \
  } while (0)

__global__ __launch_bounds__(512, 2) void gemm256(const ushort* __restrict__ A,
                                                  const ushort* __restrict__ B,
                                                  float* __restrict__ C,
                                                  const float* __restrict__ scalep,
                                                  const float* __restrict__ wscale2p) {
  extern __shared__ __align__(16) ushort lds[];   // 163840 B
  const int tid = threadIdx.x;
  const int wave = tid >> 6;
  const int lane = tid & 63;
  const int wm = wave >> 2;        // 0..1 -> 128 C-rows
  const int wn = wave & 3;         // 0..3 -> 64 C-cols
  const int lr = lane & 31;        // row-in-tile (A) / col-in-tile (B)
  const int lh = lane >> 5;        // k-half selector

  const int wg = blockIdx.x;
  const int swz = (wg & 7) * 32 + (wg >> 3);      // 256 % 8 == 0 -> bijective
  const int m0 = (swz >> 4) * BM;
  const int n0 = (swz & 15) * BN;

  f32x16 acc[4][2];
#pragma unroll
  for (int mt = 0; mt < 4; ++mt)
#pragma unroll
    for (int nt = 0; nt < 2; ++nt)
#pragma unroll
      for (int r = 0; r < 16; ++r) acc[mt][nt][r] = 0.f;

  // rotating LDS slot pointers
  ushort* pA0 = lds;                  // A read slot (tile kt)
  ushort* pA1 = lds + TILE_E;         // A tile kt+1
  ushort* pA2 = lds + 2 * TILE_E;     // A stage target (tile kt+2)
  ushort* pB0 = lds + 3 * TILE_E;     // B read slot (tile kt)
  ushort* pB1 = lds + 4 * TILE_E;     // B tile kt+1

  // staging geometry: row = h*128 + rr*64 + wave*8 + lane/8; global source chunk
  // pre-swizzled (c ^ (row&7)) -> LDS[row][p] holds chunk p^(row&7).
  int goffA[4], goffB[4], loff[4];
#pragma unroll
  for (int h = 0; h < 2; ++h)
#pragma unroll
    for (int rr = 0; rr < 2; ++rr) {
      const int idx = h * 2 + rr;
      const int rowb = h * 128 + rr * 64 + wave * 8;
      const int trow = rowb + (lane >> 3);
      const int sc = (lane & 7) ^ (trow & 7);
      goffA[idx] = (m0 + trow) * Kdim + sc * 8;
      goffB[idx] = (n0 + trow) * Kdim + sc * 8;
      loff[idx] = rowb * 64;
    }

#define STAGE_A(h, kcol)                                                       \
  do {                                                                         \
    gload_lds16(A + (size_t)goffA[(h)*2 + 0] + (kcol), pA2 + loff[(h)*2 + 0]); \
    gload_lds16(A + (size_t)goffA[(h)*2 + 1] + (kcol), pA2 + loff[(h)*2 + 1]); \
  } while (0)
#define STAGE_B(h, kcol)                                                       \
  do {                                                                         \
    gload_lds16(B + (size_t)goffB[(h)*2 + 0] + (kcol), pB0 + loff[(h)*2 + 0]); \
    gload_lds16(B + (size_t)goffB[(h)*2 + 1] + (kcol), pB0 + loff[(h)*2 + 1]); \
  } while (0)

  // fragment read geometry: elem offset = row*64 + ((c ^ (row&7))*8); c = 2*s + lh
  const int laneA = (wm * 128 + lr) * 64;
  const int laneB = (wn * 64 + lr) * 64;
  int xk[4];
#pragma unroll
  for (int s = 0; s < 4; ++s) xk[s] = ((2 * s + lh) ^ (lr & 7)) * 8;

#define RD_A(dst, base, mt)                                                \
  do {                                                                     \
    _Pragma("unroll")                                                      \
    for (int s = 0; s < 4; ++s)                                            \
      dst[s] = *(const bf16x8*)((base) + (mt) * 2048 + xk[s]);             \
  } while (0)
#define RD_B(dst, base)                                                    \
  do {                                                                     \
    _Pragma("unroll")                                                      \
    for (int nt = 0; nt < 2; ++nt)                                         \
      _Pragma("unroll")                                                    \
      for (int s = 0; s < 4; ++s)                                          \
        dst[nt][s] = *(const bf16x8*)((base) + nt * 2048 + xk[s]);         \
  } while (0)

#define MFMA_T(mt, AF)                                                           \
  do {                                                                           \
    __builtin_amdgcn_s_setprio(1);                                               \
    _Pragma("unroll")                                                            \
    for (int s = 0; s < 4; ++s) {                                                \
      acc[mt][0] = __builtin_amdgcn_mfma_f32_32x32x16_bf16(AF[s], bfr[0][s],     \
                                                           acc[mt][0], 0, 0, 0); \
      acc[mt][1] = __builtin_amdgcn_mfma_f32_32x32x16_bf16(AF[s], bfr[1][s],     \
                                                           acc[mt][1], 0, 0, 0); \
    }                                                                            \
    __builtin_amdgcn_s_setprio(0);                                               \
  } while (0)

  // ---- prologue: stage A0,B0 (->slot0), A1 (->slot1), B1 (->Bslot1) ----
  {
    ushort* sv = pA2;
    pA2 = pA0; STAGE_A(0, 0); STAGE_A(1, 0);
    STAGE_B(0, 0); STAGE_B(1, 0);
    pA2 = pA1; STAGE_A(0, BK); STAGE_A(1, BK);
    { ushort* t = pB0; pB0 = pB1; STAGE_B(0, BK); STAGE_B(1, BK); pB0 = t; }
    pA2 = sv;
  }
  asm volatile("s_waitcnt vmcnt(8)" ::: "memory");   // tile0 landed; tile1 in flight
  BAR();

  bf16x8 af0[4], af1[4], af2[4], af3[4], bfr[2][4];
  RD_A(af0, pA0 + laneA, 0);
  RD_B(bfr, pB0 + laneB);

  for (int kt = 0; kt < NT; ++kt) {
    const int kc = (kt + 2) * BK;
    const bool stg = (kt + 2) < NT;
    const bool nxt = (kt + 1) < NT;
    const ushort* aB = pA0 + laneA;

    // ---- ph0: read af1 (mt1); stage A(kt+2)h0; BAR; MFMA mt0; BAR ----
    RD_A(af1, aB, 1);
    if (stg) STAGE_A(0, kc);
    BAR();
    MFMA_T(0, af0);
    BAR();

    // ---- ph1: read af2; stage A(kt+2)h1; BAR; MFMA mt1; BAR ----
    RD_A(af2, aB, 2);
    if (stg) STAGE_A(1, kc);
    BAR();
    MFMA_T(1, af1);
    BAR();

    // ---- ph2: read af3; stage B(kt+2)h0; BAR; MFMA mt2; vmcnt(6); BAR ----
    RD_A(af3, aB, 3);
    if (stg) STAGE_B(0, kc);
    BAR();
    MFMA_T(2, af2);
    if (stg) asm volatile("s_waitcnt vmcnt(6)" ::: "memory");  // tile kt+1 landed
    else     asm volatile("s_waitcnt vmcnt(0)" ::: "memory");
    BAR();

    // ---- ph3: stage B(kt+2)h1; BAR; MFMA mt3; read next tile's af0+bfr; BAR ----
    if (stg) STAGE_B(1, kc);
    BAR();
    MFMA_T(3, af3);
    if (nxt) {
      RD_A(af0, pA1 + laneA, 0);
      RD_B(bfr, pB1 + laneB);
    }
    BAR();

    // rotate slots: A three-way, B swap
    { ushort* t = pA0; pA0 = pA1; pA1 = pA2; pA2 = t; }
    { ushort* t = pB0; pB0 = pB1; pB1 = t; }
  }

  const float alpha = scalep[0] * wscale2p[0];
#pragma unroll
  for (int mt = 0; mt < 4; ++mt)
#pragma unroll
    for (int nt = 0; nt < 2; ++nt) {
      const int col = n0 + wn * 64 + nt * 32 + lr;
      const int rbase = m0 + wm * 128 + mt * 32 + 4 * lh;
#pragma unroll
      for (int r = 0; r < 16; ++r) {
        const int row = rbase + (r & 3) + 8 * (r >> 2);
        __builtin_nontemporal_store(alpha * acc[mt][nt][r], &C[(size_t)row * Ndim + col]);
      }
    }
}

// ---------------- launcher ----------------

extern "C" void kernel_launch(void* const* d_in, const int* in_sizes, int n_in,
                              void* d_out, int out_size, void* d_ws, size_t ws_size,
                              hipStream_t stream) {
  const float* x       = (const float*)d_in[0];
  const int*   w       = (const int*)d_in[1];
  const float* wscale  = (const float*)d_in[2];
  const float* wscale2 = (const float*)d_in[3];
  const float* scale   = (const float*)d_in[4];
  float* out = (float*)d_out;

  ushort* a_deq = (ushort*)d_ws;                       // 32 MB
  ushort* b_deq = a_deq + (size_t)Mdim * Kdim;         // 32 MB

  prep_kernel<<<Mdim + Ndim, 256, 0, stream>>>(x, w, wscale, scale, a_deq, b_deq);

  (void)hipFuncSetAttribute((const void*)gemm256, hipFuncAttributeMaxDynamicSharedMemorySize, 163840);
  gemm256<<<(Mdim / BM) * (Ndim / BN), 512, 163840, stream>>>(a_deq, b_deq, out, scale, wscale2);
}

// Round 11
// 151.647 us; speedup vs baseline: 1.1167x; 1.0542x over previous
//
#include <hip/hip_runtime.h>
#include <math.h>

typedef unsigned int uint;
typedef unsigned short ushort;
typedef __attribute__((ext_vector_type(8))) short bf16x8;
typedef __attribute__((ext_vector_type(4))) float f32x4;

static constexpr int Mdim = 4096;
static constexpr int Ndim = 4096;
static constexpr int Kdim = 4096;
static constexpr int Hdim = 4096;

// ---------------- numerics helpers ----------------

__device__ __forceinline__ float fp8_round(float v) {
  float a = fabsf(v);
  float q;
  if (a >= 0x1p-6f) {           // normal range: quantum 2^(e-3)
    uint u = __float_as_uint(a);
    int e = (int)(u >> 23) - 127;
    float quant = __uint_as_float((uint)(e - 3 + 127) << 23);
    q = rintf(a / quant) * quant;
    q = fminf(q, 448.f);
  } else {                      // subnormal: quantum 2^-9
    q = rintf(a * 512.f) * 0x1p-9f;
  }
  return copysignf(q, v);
}

__device__ __forceinline__ float e2m1_round(float t) {
  float a = fabsf(t);
  float q;
  if (a <= 0.25f) q = 0.f;
  else if (a <= 0.75f) q = 0.5f;
  else if (a <= 1.25f) q = 1.f;
  else if (a <= 1.75f) q = 1.5f;
  else if (a <= 2.5f)  q = 2.f;
  else if (a <= 3.5f)  q = 3.f;
  else if (a <= 5.f)   q = 4.f;
  else                 q = 6.f;
  return copysignf(q, t);
}

__device__ __forceinline__ float e2m1_decode(uint c) {
  uint m = c & 7u;
  float v;
  if (m == 0u) v = 0.f;
  else if (m == 1u) v = 0.5f;
  else v = __uint_as_float(((126u + (m >> 1)) << 23) | ((m & 1u) << 22));
  return (c & 8u) ? -v : v;
}

// ---------------- merged prep kernel (HBM-roofline) ----------------
// blocks [0, 4096): SiLU-mul + NVFP4 fake-quant row of a_deq
// blocks [4096, 8192): weight nibble unpack + fp8-scale dequant row of b_deq

__global__ void prep_kernel(const float* __restrict__ x, const int* __restrict__ w,
                            const float* __restrict__ wscale,
                            const float* __restrict__ scalep,
                            ushort* __restrict__ a_deq, ushort* __restrict__ b_deq) {
  const int b = blockIdx.x;
  if (b < Mdim) {
    const int row = b;
    const int blk = threadIdx.x;
    const float gs = 1.0f / scalep[0];
    const float c6 = gs / 6.0f;
    const float* gp = x + (size_t)row * (2 * Hdim) + blk * 16;
    const float* up = gp + Hdim;
    float y[16];
    float amax = 0.f;
#pragma unroll
    for (int i = 0; i < 4; ++i) {
      float4 gv = ((const float4*)gp)[i];
      float4 uv = ((const float4*)up)[i];
      float ga[4] = {gv.x, gv.y, gv.z, gv.w};
      float ua[4] = {uv.x, uv.y, uv.z, uv.w};
#pragma unroll
      for (int j = 0; j < 4; ++j) {
        float xv = ga[j];
        float sig = 1.0f / (1.0f + expf(-xv));
        float yy = xv * sig * ua[j];
        y[i * 4 + j] = yy;
        amax = fmaxf(amax, fabsf(yy));
      }
    }
    const float sf = fp8_round(amax * c6);
    uint outp[8];
    if (sf > 0.f) {
      const float inv = gs / sf;
#pragma unroll
      for (int i = 0; i < 8; ++i) {
        float t0 = fminf(fmaxf(y[2 * i] * inv, -6.f), 6.f);
        float t1 = fminf(fmaxf(y[2 * i + 1] * inv, -6.f), 6.f);
        float d0 = e2m1_round(t0) * sf;   // exact in bf16 (<=5 sig bits)
        float d1 = e2m1_round(t1) * sf;
        outp[i] = (__float_as_uint(d0) >> 16) | ((__float_as_uint(d1) >> 16) << 16);
      }
    } else {
#pragma unroll
      for (int i = 0; i < 8; ++i) outp[i] = 0u;
    }
    uint4* dst = (uint4*)(a_deq + (size_t)row * Hdim + blk * 16);
    dst[0] = (uint4){outp[0], outp[1], outp[2], outp[3]};
    dst[1] = (uint4){outp[4], outp[5], outp[6], outp[7]};
  } else {
    const int n = b - Mdim;
    const int blk = threadIdx.x;
    const int4* wp = (const int4*)(w + (size_t)n * (Hdim / 2) + blk * 8);
    int4 w0 = wp[0], w1 = wp[1];
    int wb[8] = {w0.x, w0.y, w0.z, w0.w, w1.x, w1.y, w1.z, w1.w};
    const float ws = fp8_round(wscale[(size_t)n * (Hdim / 16) + blk]);
    uint outp[8];
#pragma unroll
    for (int i = 0; i < 8; ++i) {
      uint byte = (uint)wb[i] & 0xFFu;
      float vlo = e2m1_decode(byte & 15u) * ws;   // low nibble = even k
      float vhi = e2m1_decode(byte >> 4) * ws;
      outp[i] = (__float_as_uint(vlo) >> 16) | ((__float_as_uint(vhi) >> 16) << 16);
    }
    uint4* dst = (uint4*)(b_deq + (size_t)n * Hdim + blk * 16);
    dst[0] = (uint4){outp[0], outp[1], outp[2], outp[3]};
    dst[1] = (uint4){outp[4], outp[5], outp[6], outp[7]};
  }
}

// ---------------- kernel 3: 256x256 bf16 GEMM (best measured: R3/R8 structure) ----------------
// 8 waves (2M x 4N), BK=64, 16x16x32 MFMA. LDS 160 KB: A x3 (96 KB) + B x2 (64 KB).
// Pipelined ds_reads one phase ahead; stages A(kt+2)h0@ph0, h1@ph1, B(kt+2)h0@ph2,
// h1@ph3; vmcnt(6) checkpoint at ph2 (forces tile kt+1 landed). Two barriers per
// phase. Compiler-scheduled (no pins). Measured: 123-124 us, MfmaUtil ~46.6%,
// SQ_LDS_BANK_CONFLICT = 0. (32x32x16 variant: +1.26e7 conflicts, net loss - R9/R10.)

#define BM 256
#define BN 256
#define BK 64
#define NT (Kdim / BK)
#define TILE_E (256 * 64)     // 16384 ushort = 32 KB

__device__ __forceinline__ void gload_lds16(const ushort* g, ushort* l) {
  __builtin_amdgcn_global_load_lds((const __attribute__((address_space(1))) void*)g,
                                   (__attribute__((address_space(3))) void*)l,
                                   16, 0, 0);
}

#define BAR()                                   \
  do {                                          \
    asm volatile("" ::: "memory");              \
    __builtin_amdgcn_s_barrier();               \
    asm volatile("" ::: "memory");              \
  } while (0)

__global__ __launch_bounds__(512, 2) void gemm256(const ushort* __restrict__ A,
                                                  const ushort* __restrict__ B,
                                                  float* __restrict__ C,
                                                  const float* __restrict__ scalep,
                                                  const float* __restrict__ wscale2p) {
  extern __shared__ __align__(16) ushort lds[];   // 163840 B
  const int tid = threadIdx.x;
  const int wave = tid >> 6;
  const int lane = tid & 63;
  const int wm = wave >> 2;
  const int wn = wave & 3;
  const int fr = lane & 15;
  const int fq = lane >> 4;

  const int wg = blockIdx.x;
  const int swz = (wg & 7) * 32 + (wg >> 3);      // 256 % 8 == 0 -> bijective
  const int m0 = (swz >> 4) * BM;
  const int n0 = (swz & 15) * BN;

  f32x4 acc[8][4];
#pragma unroll
  for (int i = 0; i < 8; ++i)
#pragma unroll
    for (int j = 0; j < 4; ++j) acc[i][j] = (f32x4){0.f, 0.f, 0.f, 0.f};

  // rotating LDS slot pointers
  ushort* pA0 = lds;                  // A read slot (tile kt)
  ushort* pA1 = lds + TILE_E;         // A tile kt+1
  ushort* pA2 = lds + 2 * TILE_E;     // A stage target (tile kt+2)
  ushort* pB0 = lds + 3 * TILE_E;     // B read slot (tile kt)
  ushort* pB1 = lds + 4 * TILE_E;     // B tile kt+1

  // staging geometry: row = h*128 + rr*64 + wave*8 + lane/8; global source chunk
  // pre-swizzled (c ^ (row&7)) -> LDS[row][p] holds chunk p^(row&7).
  int goffA[4], goffB[4], loff[4];
#pragma unroll
  for (int h = 0; h < 2; ++h)
#pragma unroll
    for (int rr = 0; rr < 2; ++rr) {
      const int idx = h * 2 + rr;
      const int rowb = h * 128 + rr * 64 + wave * 8;
      const int trow = rowb + (lane >> 3);
      const int sc = (lane & 7) ^ (trow & 7);
      goffA[idx] = (m0 + trow) * Kdim + sc * 8;
      goffB[idx] = (n0 + trow) * Kdim + sc * 8;
      loff[idx] = rowb * 64;
    }

#define STAGE_A(h, kcol)                                                       \
  do {                                                                         \
    gload_lds16(A + (size_t)goffA[(h)*2 + 0] + (kcol), pA2 + loff[(h)*2 + 0]); \
    gload_lds16(A + (size_t)goffA[(h)*2 + 1] + (kcol), pA2 + loff[(h)*2 + 1]); \
  } while (0)
#define STAGE_B(h, kcol)                                                       \
  do {                                                                         \
    gload_lds16(B + (size_t)goffB[(h)*2 + 0] + (kcol), pB0 + loff[(h)*2 + 0]); \
    gload_lds16(B + (size_t)goffB[(h)*2 + 1] + (kcol), pB0 + loff[(h)*2 + 1]); \
  } while (0)

  // fragment read geometry: elem offset = row*64 + ((c ^ (row&7))*8)
  const int laneAOff = (wm * 128 + fr) * 64;
  const int laneBOff = (wn * 64 + fr) * 64;
  const int xo0 = (fq ^ (fr & 7)) * 8;            // kk = 0
  const int xo1 = ((4 + fq) ^ (fr & 7)) * 8;      // kk = 1

  // ---- prologue: stage A0,B0 (->slot0), A1 (->slot1), B1 (->Bslot1) ----
  {
    ushort* sv = pA2;
    pA2 = pA0; STAGE_A(0, 0); STAGE_A(1, 0);
    STAGE_B(0, 0); STAGE_B(1, 0);
    pA2 = pA1; STAGE_A(0, BK); STAGE_A(1, BK);
    { ushort* t = pB0; pB0 = pB1; STAGE_B(0, BK); STAGE_B(1, BK); pB0 = t; }
    pA2 = sv;
  }
  asm volatile("s_waitcnt vmcnt(8)" ::: "memory");   // tile0 landed; tile1 in flight
  BAR();

  bf16x8 af0[2][2], bfr[4][2];
  {
    const ushort* aR0 = pA0 + laneAOff + xo0;
    const ushort* aR1 = pA0 + laneAOff + xo1;
    const ushort* bR0 = pB0 + laneBOff + xo0;
    const ushort* bR1 = pB0 + laneBOff + xo1;
#pragma unroll
    for (int ni = 0; ni < 4; ++ni) {
      bfr[ni][0] = *(const bf16x8*)(bR0 + ni * 1024);
      bfr[ni][1] = *(const bf16x8*)(bR1 + ni * 1024);
    }
#pragma unroll
    for (int m2 = 0; m2 < 2; ++m2) {
      af0[m2][0] = *(const bf16x8*)(aR0 + m2 * 1024);
      af0[m2][1] = *(const bf16x8*)(aR1 + m2 * 1024);
    }
  }

  for (int kt = 0; kt < NT; ++kt) {
    const int kc = (kt + 2) * BK;
    const bool stg = (kt + 2) < NT;
    const bool nxt = (kt + 1) < NT;
    const ushort* aR0 = pA0 + laneAOff + xo0;
    const ushort* aR1 = pA0 + laneAOff + xo1;
    bf16x8 af1[2][2], af2[2][2], af3[2][2];

    // ---- ph0: read af1; stage A(kt+2)h0; MFMA rows 0-1 ----
#pragma unroll
    for (int m2 = 0; m2 < 2; ++m2) {
      af1[m2][0] = *(const bf16x8*)(aR0 + (2 + m2) * 1024);
      af1[m2][1] = *(const bf16x8*)(aR1 + (2 + m2) * 1024);
    }
    if (stg) STAGE_A(0, kc);
    BAR();
    __builtin_amdgcn_s_setprio(1);
#pragma unroll
    for (int m2 = 0; m2 < 2; ++m2)
#pragma unroll
      for (int ni = 0; ni < 4; ++ni)
#pragma unroll
        for (int kk = 0; kk < 2; ++kk)
          acc[m2][ni] = __builtin_amdgcn_mfma_f32_16x16x32_bf16(af0[m2][kk], bfr[ni][kk],
                                                                acc[m2][ni], 0, 0, 0);
    __builtin_amdgcn_s_setprio(0);
    BAR();

    // ---- ph1: read af2; stage A(kt+2)h1; MFMA rows 2-3 ----
#pragma unroll
    for (int m2 = 0; m2 < 2; ++m2) {
      af2[m2][0] = *(const bf16x8*)(aR0 + (4 + m2) * 1024);
      af2[m2][1] = *(const bf16x8*)(aR1 + (4 + m2) * 1024);
    }
    if (stg) STAGE_A(1, kc);
    BAR();
    __builtin_amdgcn_s_setprio(1);
#pragma unroll
    for (int m2 = 0; m2 < 2; ++m2)
#pragma unroll
      for (int ni = 0; ni < 4; ++ni)
#pragma unroll
        for (int kk = 0; kk < 2; ++kk)
          acc[2 + m2][ni] = __builtin_amdgcn_mfma_f32_16x16x32_bf16(af1[m2][kk], bfr[ni][kk],
                                                                    acc[2 + m2][ni], 0, 0, 0);
    __builtin_amdgcn_s_setprio(0);
    BAR();

    // ---- ph2: read af3; stage B(kt+2)h0; MFMA rows 4-5; vmcnt checkpoint ----
#pragma unroll
    for (int m2 = 0; m2 < 2; ++m2) {
      af3[m2][0] = *(const bf16x8*)(aR0 + (6 + m2) * 1024);
      af3[m2][1] = *(const bf16x8*)(aR1 + (6 + m2) * 1024);
    }
    if (stg) STAGE_B(0, kc);
    BAR();
    __builtin_amdgcn_s_setprio(1);
#pragma unroll
    for (int m2 = 0; m2 < 2; ++m2)
#pragma unroll
      for (int ni = 0; ni < 4; ++ni)
#pragma unroll
        for (int kk = 0; kk < 2; ++kk)
          acc[4 + m2][ni] = __builtin_amdgcn_mfma_f32_16x16x32_bf16(af2[m2][kk], bfr[ni][kk],
                                                                    acc[4 + m2][ni], 0, 0, 0);
    __builtin_amdgcn_s_setprio(0);
    if (stg) asm volatile("s_waitcnt vmcnt(6)" ::: "memory");  // forces tile kt+1 landed
    else     asm volatile("s_waitcnt vmcnt(0)" ::: "memory");
    BAR();

    // ---- ph3: stage B(kt+2)h1; MFMA rows 6-7; then read next tile's bfr+af0 ----
    if (stg) STAGE_B(1, kc);
    BAR();
    __builtin_amdgcn_s_setprio(1);
#pragma unroll
    for (int m2 = 0; m2 < 2; ++m2)
#pragma unroll
      for (int ni = 0; ni < 4; ++ni)
#pragma unroll
        for (int kk = 0; kk < 2; ++kk)
          acc[6 + m2][ni] = __builtin_amdgcn_mfma_f32_16x16x32_bf16(af3[m2][kk], bfr[ni][kk],
                                                                    acc[6 + m2][ni], 0, 0, 0);
    __builtin_amdgcn_s_setprio(0);
    if (nxt) {
      const ushort* aN0 = pA1 + laneAOff + xo0;
      const ushort* aN1 = pA1 + laneAOff + xo1;
      const ushort* bN0 = pB1 + laneBOff + xo0;
      const ushort* bN1 = pB1 + laneBOff + xo1;
#pragma unroll
      for (int ni = 0; ni < 4; ++ni) {
        bfr[ni][0] = *(const bf16x8*)(bN0 + ni * 1024);
        bfr[ni][1] = *(const bf16x8*)(bN1 + ni * 1024);
      }
#pragma unroll
      for (int m2 = 0; m2 < 2; ++m2) {
        af0[m2][0] = *(const bf16x8*)(aN0 + m2 * 1024);
        af0[m2][1] = *(const bf16x8*)(aN1 + m2 * 1024);
      }
    }
    BAR();

    // rotate slots: A three-way, B swap
    { ushort* t = pA0; pA0 = pA1; pA1 = pA2; pA2 = t; }
    { ushort* t = pB0; pB0 = pB1; pB1 = t; }
  }

  const float alpha = scalep[0] * wscale2p[0];
#pragma unroll
  for (int mi = 0; mi < 8; ++mi)
#pragma unroll
    for (int ni = 0; ni < 4; ++ni) {
      const int col = n0 + wn * 64 + ni * 16 + fr;
      const int rbase = m0 + wm * 128 + mi * 16 + fq * 4;
#pragma unroll
      for (int r = 0; r < 4; ++r)
        __builtin_nontemporal_store(alpha * acc[mi][ni][r],
                                    &C[(size_t)(rbase + r) * Ndim + col]);
    }
}

// ---------------- launcher ----------------

extern "C" void kernel_launch(void* const* d_in, const int* in_sizes, int n_in,
                              void* d_out, int out_size, void* d_ws, size_t ws_size,
                              hipStream_t stream) {
  const float* x       = (const float*)d_in[0];
  const int*   w       = (const int*)d_in[1];
  const float* wscale  = (const float*)d_in[2];
  const float* wscale2 = (const float*)d_in[3];
  const float* scale   = (const float*)d_in[4];
  float* out = (float*)d_out;

  ushort* a_deq = (ushort*)d_ws;                       // 32 MB
  ushort* b_deq = a_deq + (size_t)Mdim * Kdim;         // 32 MB

  prep_kernel<<<Mdim + Ndim, 256, 0, stream>>>(x, w, wscale, scale, a_deq, b_deq);

  (void)hipFuncSetAttribute((const void*)gemm256, hipFuncAttributeMaxDynamicSharedMemorySize, 163840);
  gemm256<<<(Mdim / BM) * (Ndim / BN), 512, 163840, stream>>>(a_deq, b_deq, out, scale, wscale2);
}

// Round 12
// 149.794 us; speedup vs baseline: 1.1305x; 1.0124x over previous
//
#include <hip/hip_runtime.h>
#include <math.h>

typedef unsigned int uint;
typedef unsigned short ushort;
typedef __attribute__((ext_vector_type(8))) short bf16x8;
typedef __attribute__((ext_vector_type(4))) float f32x4;

static constexpr int Mdim = 4096;
static constexpr int Ndim = 4096;
static constexpr int Kdim = 4096;
static constexpr int Hdim = 4096;

// ---------------- numerics helpers ----------------

__device__ __forceinline__ float fp8_round(float v) {
  float a = fabsf(v);
  float q;
  if (a >= 0x1p-6f) {           // normal range: quantum 2^(e-3)
    uint u = __float_as_uint(a);
    int e = (int)(u >> 23) - 127;
    float quant = __uint_as_float((uint)(e - 3 + 127) << 23);
    q = rintf(a / quant) * quant;
    q = fminf(q, 448.f);
  } else {                      // subnormal: quantum 2^-9
    q = rintf(a * 512.f) * 0x1p-9f;
  }
  return copysignf(q, v);
}

__device__ __forceinline__ float e2m1_round(float t) {
  float a = fabsf(t);
  float q;
  if (a <= 0.25f) q = 0.f;
  else if (a <= 0.75f) q = 0.5f;
  else if (a <= 1.25f) q = 1.f;
  else if (a <= 1.75f) q = 1.5f;
  else if (a <= 2.5f)  q = 2.f;
  else if (a <= 3.5f)  q = 3.f;
  else if (a <= 5.f)   q = 4.f;
  else                 q = 6.f;
  return copysignf(q, t);
}

__device__ __forceinline__ float e2m1_decode(uint c) {
  uint m = c & 7u;
  float v;
  if (m == 0u) v = 0.f;
  else if (m == 1u) v = 0.5f;
  else v = __uint_as_float(((126u + (m >> 1)) << 23) | ((m & 1u) << 22));
  return (c & 8u) ? -v : v;
}

// ---------------- merged prep kernel (HBM/L3-roofline) ----------------

__global__ void prep_kernel(const float* __restrict__ x, const int* __restrict__ w,
                            const float* __restrict__ wscale,
                            const float* __restrict__ scalep,
                            ushort* __restrict__ a_deq, ushort* __restrict__ b_deq) {
  const int b = blockIdx.x;
  if (b < Mdim) {
    const int row = b;
    const int blk = threadIdx.x;
    const float gs = 1.0f / scalep[0];
    const float c6 = gs / 6.0f;
    const float* gp = x + (size_t)row * (2 * Hdim) + blk * 16;
    const float* up = gp + Hdim;
    float y[16];
    float amax = 0.f;
#pragma unroll
    for (int i = 0; i < 4; ++i) {
      float4 gv = ((const float4*)gp)[i];
      float4 uv = ((const float4*)up)[i];
      float ga[4] = {gv.x, gv.y, gv.z, gv.w};
      float ua[4] = {uv.x, uv.y, uv.z, uv.w};
#pragma unroll
      for (int j = 0; j < 4; ++j) {
        float xv = ga[j];
        float sig = 1.0f / (1.0f + expf(-xv));
        float yy = xv * sig * ua[j];
        y[i * 4 + j] = yy;
        amax = fmaxf(amax, fabsf(yy));
      }
    }
    const float sf = fp8_round(amax * c6);
    uint outp[8];
    if (sf > 0.f) {
      const float inv = gs / sf;
#pragma unroll
      for (int i = 0; i < 8; ++i) {
        float t0 = fminf(fmaxf(y[2 * i] * inv, -6.f), 6.f);
        float t1 = fminf(fmaxf(y[2 * i + 1] * inv, -6.f), 6.f);
        float d0 = e2m1_round(t0) * sf;   // exact in bf16 (<=5 sig bits)
        float d1 = e2m1_round(t1) * sf;
        outp[i] = (__float_as_uint(d0) >> 16) | ((__float_as_uint(d1) >> 16) << 16);
      }
    } else {
#pragma unroll
      for (int i = 0; i < 8; ++i) outp[i] = 0u;
    }
    uint4* dst = (uint4*)(a_deq + (size_t)row * Hdim + blk * 16);
    dst[0] = (uint4){outp[0], outp[1], outp[2], outp[3]};
    dst[1] = (uint4){outp[4], outp[5], outp[6], outp[7]};
  } else {
    const int n = b - Mdim;
    const int blk = threadIdx.x;
    const int4* wp = (const int4*)(w + (size_t)n * (Hdim / 2) + blk * 8);
    int4 w0 = wp[0], w1 = wp[1];
    int wb[8] = {w0.x, w0.y, w0.z, w0.w, w1.x, w1.y, w1.z, w1.w};
    const float ws = fp8_round(wscale[(size_t)n * (Hdim / 16) + blk]);
    uint outp[8];
#pragma unroll
    for (int i = 0; i < 8; ++i) {
      uint byte = (uint)wb[i] & 0xFFu;
      float vlo = e2m1_decode(byte & 15u) * ws;   // low nibble = even k
      float vhi = e2m1_decode(byte >> 4) * ws;
      outp[i] = (__float_as_uint(vlo) >> 16) | ((__float_as_uint(vhi) >> 16) << 16);
    }
    uint4* dst = (uint4*)(b_deq + (size_t)n * Hdim + blk * 16);
    dst[0] = (uint4){outp[0], outp[1], outp[2], outp[3]};
    dst[1] = (uint4){outp[4], outp[5], outp[6], outp[7]};
  }
}

// ---------------- kernel 3: 256x256 bf16 GEMM, R8 dataflow + 1 barrier/phase ----------------
// 8 waves (2M x 4N), BK=64, 16x16x32 MFMA (0-conflict geometry). LDS 160 KB:
// A x3 + B x2. Reads one phase ahead; stages A(kt+2)h0@ph0, h1@ph1, B(kt+2)h0@ph2,
// h1@ph3; vmcnt(6)@ph2. SINGLE barrier per phase (R9-validated ledger: every slot
// overwrite is >=1 barrier after its last reader's compiler-forced lgkm completion;
// staged slots are disjoint from all possibly-in-flight reads).

#define BM 256
#define BN 256
#define BK 64
#define NT (Kdim / BK)
#define TILE_E (256 * 64)     // 16384 ushort = 32 KB

__device__ __forceinline__ void gload_lds16(const ushort* g, ushort* l) {
  __builtin_amdgcn_global_load_lds((const __attribute__((address_space(1))) void*)g,
                                   (__attribute__((address_space(3))) void*)l,
                                   16, 0, 0);
}

#define BAR()                                   \
  do {                                          \
    asm volatile("" ::: "memory");              \
    __builtin_amdgcn_s_barrier();               \
    asm volatile("" ::: "memory");              \
  } while (0)

__global__ __launch_bounds__(512, 2) void gemm256(const ushort* __restrict__ A,
                                                  const ushort* __restrict__ B,
                                                  float* __restrict__ C,
                                                  const float* __restrict__ scalep,
                                                  const float* __restrict__ wscale2p) {
  extern __shared__ __align__(16) ushort lds[];   // 163840 B
  const int tid = threadIdx.x;
  const int wave = tid >> 6;
  const int lane = tid & 63;
  const int wm = wave >> 2;
  const int wn = wave & 3;
  const int fr = lane & 15;
  const int fq = lane >> 4;

  const int wg = blockIdx.x;
  const int swz = (wg & 7) * 32 + (wg >> 3);      // 256 % 8 == 0 -> bijective
  const int m0 = (swz >> 4) * BM;
  const int n0 = (swz & 15) * BN;

  f32x4 acc[8][4];
#pragma unroll
  for (int i = 0; i < 8; ++i)
#pragma unroll
    for (int j = 0; j < 4; ++j) acc[i][j] = (f32x4){0.f, 0.f, 0.f, 0.f};

  ushort* pA0 = lds;                  // A read slot (tile kt)
  ushort* pA1 = lds + TILE_E;         // A tile kt+1
  ushort* pA2 = lds + 2 * TILE_E;     // A stage target (tile kt+2)
  ushort* pB0 = lds + 3 * TILE_E;     // B read slot (tile kt)
  ushort* pB1 = lds + 4 * TILE_E;     // B tile kt+1

  int goffA[4], goffB[4], loff[4];
#pragma unroll
  for (int h = 0; h < 2; ++h)
#pragma unroll
    for (int rr = 0; rr < 2; ++rr) {
      const int idx = h * 2 + rr;
      const int rowb = h * 128 + rr * 64 + wave * 8;
      const int trow = rowb + (lane >> 3);
      const int sc = (lane & 7) ^ (trow & 7);
      goffA[idx] = (m0 + trow) * Kdim + sc * 8;
      goffB[idx] = (n0 + trow) * Kdim + sc * 8;
      loff[idx] = rowb * 64;
    }

#define STAGE_A(h, kcol)                                                       \
  do {                                                                         \
    gload_lds16(A + (size_t)goffA[(h)*2 + 0] + (kcol), pA2 + loff[(h)*2 + 0]); \
    gload_lds16(A + (size_t)goffA[(h)*2 + 1] + (kcol), pA2 + loff[(h)*2 + 1]); \
  } while (0)
#define STAGE_B(h, kcol)                                                       \
  do {                                                                         \
    gload_lds16(B + (size_t)goffB[(h)*2 + 0] + (kcol), pB0 + loff[(h)*2 + 0]); \
    gload_lds16(B + (size_t)goffB[(h)*2 + 1] + (kcol), pB0 + loff[(h)*2 + 1]); \
  } while (0)

  const int laneAOff = (wm * 128 + fr) * 64;
  const int laneBOff = (wn * 64 + fr) * 64;
  const int xo0 = (fq ^ (fr & 7)) * 8;
  const int xo1 = ((4 + fq) ^ (fr & 7)) * 8;

  // ---- prologue: stage A0,B0 (->slot0), A1 (->slot1), B1 (->Bslot1) ----
  {
    ushort* sv = pA2;
    pA2 = pA0; STAGE_A(0, 0); STAGE_A(1, 0);
    STAGE_B(0, 0); STAGE_B(1, 0);
    pA2 = pA1; STAGE_A(0, BK); STAGE_A(1, BK);
    { ushort* t = pB0; pB0 = pB1; STAGE_B(0, BK); STAGE_B(1, BK); pB0 = t; }
    pA2 = sv;
  }
  asm volatile("s_waitcnt vmcnt(8)" ::: "memory");   // tile0 landed; tile1 in flight
  BAR();

  bf16x8 af0[2][2], bfr[4][2];
  {
    const ushort* aR0 = pA0 + laneAOff + xo0;
    const ushort* aR1 = pA0 + laneAOff + xo1;
    const ushort* bR0 = pB0 + laneBOff + xo0;
    const ushort* bR1 = pB0 + laneBOff + xo1;
#pragma unroll
    for (int ni = 0; ni < 4; ++ni) {
      bfr[ni][0] = *(const bf16x8*)(bR0 + ni * 1024);
      bfr[ni][1] = *(const bf16x8*)(bR1 + ni * 1024);
    }
#pragma unroll
    for (int m2 = 0; m2 < 2; ++m2) {
      af0[m2][0] = *(const bf16x8*)(aR0 + m2 * 1024);
      af0[m2][1] = *(const bf16x8*)(aR1 + m2 * 1024);
    }
  }

  for (int kt = 0; kt < NT; ++kt) {
    const int kc = (kt + 2) * BK;
    const bool stg = (kt + 2) < NT;
    const bool nxt = (kt + 1) < NT;
    const ushort* aR0 = pA0 + laneAOff + xo0;
    const ushort* aR1 = pA0 + laneAOff + xo1;
    bf16x8 af1[2][2], af2[2][2], af3[2][2];

    // ---- ph0: read af1; stage A(kt+2)h0; MFMA rows 0-1; BAR ----
#pragma unroll
    for (int m2 = 0; m2 < 2; ++m2) {
      af1[m2][0] = *(const bf16x8*)(aR0 + (2 + m2) * 1024);
      af1[m2][1] = *(const bf16x8*)(aR1 + (2 + m2) * 1024);
    }
    if (stg) STAGE_A(0, kc);
    __builtin_amdgcn_s_setprio(1);
#pragma unroll
    for (int m2 = 0; m2 < 2; ++m2)
#pragma unroll
      for (int ni = 0; ni < 4; ++ni)
#pragma unroll
        for (int kk = 0; kk < 2; ++kk)
          acc[m2][ni] = __builtin_amdgcn_mfma_f32_16x16x32_bf16(af0[m2][kk], bfr[ni][kk],
                                                                acc[m2][ni], 0, 0, 0);
    __builtin_amdgcn_s_setprio(0);
    BAR();

    // ---- ph1: read af2; stage A(kt+2)h1; MFMA rows 2-3; BAR ----
#pragma unroll
    for (int m2 = 0; m2 < 2; ++m2) {
      af2[m2][0] = *(const bf16x8*)(aR0 + (4 + m2) * 1024);
      af2[m2][1] = *(const bf16x8*)(aR1 + (4 + m2) * 1024);
    }
    if (stg) STAGE_A(1, kc);
    __builtin_amdgcn_s_setprio(1);
#pragma unroll
    for (int m2 = 0; m2 < 2; ++m2)
#pragma unroll
      for (int ni = 0; ni < 4; ++ni)
#pragma unroll
        for (int kk = 0; kk < 2; ++kk)
          acc[2 + m2][ni] = __builtin_amdgcn_mfma_f32_16x16x32_bf16(af1[m2][kk], bfr[ni][kk],
                                                                    acc[2 + m2][ni], 0, 0, 0);
    __builtin_amdgcn_s_setprio(0);
    BAR();

    // ---- ph2: read af3; stage B(kt+2)h0; MFMA rows 4-5; vmcnt(6); BAR ----
#pragma unroll
    for (int m2 = 0; m2 < 2; ++m2) {
      af3[m2][0] = *(const bf16x8*)(aR0 + (6 + m2) * 1024);
      af3[m2][1] = *(const bf16x8*)(aR1 + (6 + m2) * 1024);
    }
    if (stg) STAGE_B(0, kc);
    __builtin_amdgcn_s_setprio(1);
#pragma unroll
    for (int m2 = 0; m2 < 2; ++m2)
#pragma unroll
      for (int ni = 0; ni < 4; ++ni)
#pragma unroll
        for (int kk = 0; kk < 2; ++kk)
          acc[4 + m2][ni] = __builtin_amdgcn_mfma_f32_16x16x32_bf16(af2[m2][kk], bfr[ni][kk],
                                                                    acc[4 + m2][ni], 0, 0, 0);
    __builtin_amdgcn_s_setprio(0);
    if (stg) asm volatile("s_waitcnt vmcnt(6)" ::: "memory");  // forces tile kt+1 landed
    else     asm volatile("s_waitcnt vmcnt(0)" ::: "memory");
    BAR();

    // ---- ph3: stage B(kt+2)h1; MFMA rows 6-7; read next tile's bfr+af0; BAR ----
    if (stg) STAGE_B(1, kc);
    __builtin_amdgcn_s_setprio(1);
#pragma unroll
    for (int m2 = 0; m2 < 2; ++m2)
#pragma unroll
      for (int ni = 0; ni < 4; ++ni)
#pragma unroll
        for (int kk = 0; kk < 2; ++kk)
          acc[6 + m2][ni] = __builtin_amdgcn_mfma_f32_16x16x32_bf16(af3[m2][kk], bfr[ni][kk],
                                                                    acc[6 + m2][ni], 0, 0, 0);
    __builtin_amdgcn_s_setprio(0);
    if (nxt) {
      const ushort* aN0 = pA1 + laneAOff + xo0;
      const ushort* aN1 = pA1 + laneAOff + xo1;
      const ushort* bN0 = pB1 + laneBOff + xo0;
      const ushort* bN1 = pB1 + laneBOff + xo1;
#pragma unroll
      for (int ni = 0; ni < 4; ++ni) {
        bfr[ni][0] = *(const bf16x8*)(bN0 + ni * 1024);
        bfr[ni][1] = *(const bf16x8*)(bN1 + ni * 1024);
      }
#pragma unroll
      for (int m2 = 0; m2 < 2; ++m2) {
        af0[m2][0] = *(const bf16x8*)(aN0 + m2 * 1024);
        af0[m2][1] = *(const bf16x8*)(aN1 + m2 * 1024);
      }
    }
    BAR();

    // rotate slots: A three-way, B swap
    { ushort* t = pA0; pA0 = pA1; pA1 = pA2; pA2 = t; }
    { ushort* t = pB0; pB0 = pB1; pB1 = t; }
  }

  const float alpha = scalep[0] * wscale2p[0];
#pragma unroll
  for (int mi = 0; mi < 8; ++mi)
#pragma unroll
    for (int ni = 0; ni < 4; ++ni) {
      const int col = n0 + wn * 64 + ni * 16 + fr;
      const int rbase = m0 + wm * 128 + mi * 16 + fq * 4;
#pragma unroll
      for (int r = 0; r < 4; ++r)
        __builtin_nontemporal_store(alpha * acc[mi][ni][r],
                                    &C[(size_t)(rbase + r) * Ndim + col]);
    }
}

// ---------------- launcher ----------------

extern "C" void kernel_launch(void* const* d_in, const int* in_sizes, int n_in,
                              void* d_out, int out_size, void* d_ws, size_t ws_size,
                              hipStream_t stream) {
  const float* x       = (const float*)d_in[0];
  const int*   w       = (const int*)d_in[1];
  const float* wscale  = (const float*)d_in[2];
  const float* wscale2 = (const float*)d_in[3];
  const float* scale   = (const float*)d_in[4];
  float* out = (float*)d_out;

  ushort* a_deq = (ushort*)d_ws;                       // 32 MB
  ushort* b_deq = a_deq + (size_t)Mdim * Kdim;         // 32 MB

  prep_kernel<<<Mdim + Ndim, 256, 0, stream>>>(x, w, wscale, scale, a_deq, b_deq);

  (void)hipFuncSetAttribute((const void*)gemm256, hipFuncAttributeMaxDynamicSharedMemorySize, 163840);
  gemm256<<<(Mdim / BM) * (Ndim / BN), 512, 163840, stream>>>(a_deq, b_deq, out, scale, wscale2);
}

// Round 13
// 149.573 us; speedup vs baseline: 1.1322x; 1.0015x over previous
//
#include <hip/hip_runtime.h>
#include <math.h>

typedef unsigned int uint;
typedef unsigned short ushort;
typedef __attribute__((ext_vector_type(8))) short bf16x8;
typedef __attribute__((ext_vector_type(4))) float f32x4;

static constexpr int Mdim = 4096;
static constexpr int Ndim = 4096;
static constexpr int Kdim = 4096;
static constexpr int Hdim = 4096;

// ---------------- numerics helpers ----------------

__device__ __forceinline__ float fp8_round(float v) {
  float a = fabsf(v);
  float q;
  if (a >= 0x1p-6f) {           // normal range: quantum 2^(e-3)
    uint u = __float_as_uint(a);
    int e = (int)(u >> 23) - 127;
    float quant = __uint_as_float((uint)(e - 3 + 127) << 23);
    q = rintf(a / quant) * quant;
    q = fminf(q, 448.f);
  } else {                      // subnormal: quantum 2^-9
    q = rintf(a * 512.f) * 0x1p-9f;
  }
  return copysignf(q, v);
}

__device__ __forceinline__ float e2m1_round(float t) {
  float a = fabsf(t);
  float q;
  if (a <= 0.25f) q = 0.f;
  else if (a <= 0.75f) q = 0.5f;
  else if (a <= 1.25f) q = 1.f;
  else if (a <= 1.75f) q = 1.5f;
  else if (a <= 2.5f)  q = 2.f;
  else if (a <= 3.5f)  q = 3.f;
  else if (a <= 5.f)   q = 4.f;
  else                 q = 6.f;
  return copysignf(q, t);
}

__device__ __forceinline__ float e2m1_decode(uint c) {
  uint m = c & 7u;
  float v;
  if (m == 0u) v = 0.f;
  else if (m == 1u) v = 0.5f;
  else v = __uint_as_float(((126u + (m >> 1)) << 23) | ((m & 1u) << 22));
  return (c & 8u) ? -v : v;
}

// ---------------- merged prep kernel (HBM/L3-roofline) ----------------

__global__ void prep_kernel(const float* __restrict__ x, const int* __restrict__ w,
                            const float* __restrict__ wscale,
                            const float* __restrict__ scalep,
                            ushort* __restrict__ a_deq, ushort* __restrict__ b_deq) {
  const int b = blockIdx.x;
  if (b < Mdim) {
    const int row = b;
    const int blk = threadIdx.x;
    const float gs = 1.0f / scalep[0];
    const float c6 = gs / 6.0f;
    const float* gp = x + (size_t)row * (2 * Hdim) + blk * 16;
    const float* up = gp + Hdim;
    float y[16];
    float amax = 0.f;
#pragma unroll
    for (int i = 0; i < 4; ++i) {
      float4 gv = ((const float4*)gp)[i];
      float4 uv = ((const float4*)up)[i];
      float ga[4] = {gv.x, gv.y, gv.z, gv.w};
      float ua[4] = {uv.x, uv.y, uv.z, uv.w};
#pragma unroll
      for (int j = 0; j < 4; ++j) {
        float xv = ga[j];
        float sig = 1.0f / (1.0f + expf(-xv));
        float yy = xv * sig * ua[j];
        y[i * 4 + j] = yy;
        amax = fmaxf(amax, fabsf(yy));
      }
    }
    const float sf = fp8_round(amax * c6);
    uint outp[8];
    if (sf > 0.f) {
      const float inv = gs / sf;
#pragma unroll
      for (int i = 0; i < 8; ++i) {
        float t0 = fminf(fmaxf(y[2 * i] * inv, -6.f), 6.f);
        float t1 = fminf(fmaxf(y[2 * i + 1] * inv, -6.f), 6.f);
        float d0 = e2m1_round(t0) * sf;   // exact in bf16 (<=5 sig bits)
        float d1 = e2m1_round(t1) * sf;
        outp[i] = (__float_as_uint(d0) >> 16) | ((__float_as_uint(d1) >> 16) << 16);
      }
    } else {
#pragma unroll
      for (int i = 0; i < 8; ++i) outp[i] = 0u;
    }
    uint4* dst = (uint4*)(a_deq + (size_t)row * Hdim + blk * 16);
    dst[0] = (uint4){outp[0], outp[1], outp[2], outp[3]};
    dst[1] = (uint4){outp[4], outp[5], outp[6], outp[7]};
  } else {
    const int n = b - Mdim;
    const int blk = threadIdx.x;
    const int4* wp = (const int4*)(w + (size_t)n * (Hdim / 2) + blk * 8);
    int4 w0 = wp[0], w1 = wp[1];
    int wb[8] = {w0.x, w0.y, w0.z, w0.w, w1.x, w1.y, w1.z, w1.w};
    const float ws = fp8_round(wscale[(size_t)n * (Hdim / 16) + blk]);
    uint outp[8];
#pragma unroll
    for (int i = 0; i < 8; ++i) {
      uint byte = (uint)wb[i] & 0xFFu;
      float vlo = e2m1_decode(byte & 15u) * ws;   // low nibble = even k
      float vhi = e2m1_decode(byte >> 4) * ws;
      outp[i] = (__float_as_uint(vlo) >> 16) | ((__float_as_uint(vhi) >> 16) << 16);
    }
    uint4* dst = (uint4*)(b_deq + (size_t)n * Hdim + blk * 16);
    dst[0] = (uint4){outp[0], outp[1], outp[2], outp[3]};
    dst[1] = (uint4){outp[4], outp[5], outp[6], outp[7]};
  }
}

// ---------------- kernel 3: 256x256 bf16 GEMM, R12 dataflow + 2 phases/K-tile ----------------
// 8 waves (2M x 4N), BK=64, 16x16x32 MFMA (0-conflict geometry). LDS 160 KB:
// A x3 + B x2. All fragments read ONE PHASE before use. Per K-tile:
//  ph0: read af2/af3 (rows 4-7, from pA0); stage A(kt+2) h0+h1 -> pA2;
//       MFMA rows 0-3 (af0/af1, read last ph1); BAR.
//  ph1: stage B(kt+2) h0+h1 -> pB0; MFMA rows 4-7 (af2/af3); vmcnt(8)
//       [= this tile's 8 staged loads -> forces A/B(kt+1) landed]; read
//       next tile's af0/af1 (pA1) + bfr (pB1); BAR.
// Slot-overwrite safety: every staged slot's previous content had its last
// ds_read lgkm-forced >=1 barrier before the stage (same rotation as R12).

#define BM 256
#define BN 256
#define BK 64
#define NT (Kdim / BK)
#define TILE_E (256 * 64)     // 16384 ushort = 32 KB

__device__ __forceinline__ void gload_lds16(const ushort* g, ushort* l) {
  __builtin_amdgcn_global_load_lds((const __attribute__((address_space(1))) void*)g,
                                   (__attribute__((address_space(3))) void*)l,
                                   16, 0, 0);
}

#define BAR()                                   \
  do {                                          \
    asm volatile("" ::: "memory");              \
    __builtin_amdgcn_s_barrier();               \
    asm volatile("" ::: "memory");              \
  } while (0)

__global__ __launch_bounds__(512, 2) void gemm256(const ushort* __restrict__ A,
                                                  const ushort* __restrict__ B,
                                                  float* __restrict__ C,
                                                  const float* __restrict__ scalep,
                                                  const float* __restrict__ wscale2p) {
  extern __shared__ __align__(16) ushort lds[];   // 163840 B
  const int tid = threadIdx.x;
  const int wave = tid >> 6;
  const int lane = tid & 63;
  const int wm = wave >> 2;
  const int wn = wave & 3;
  const int fr = lane & 15;
  const int fq = lane >> 4;

  const int wg = blockIdx.x;
  const int swz = (wg & 7) * 32 + (wg >> 3);      // 256 % 8 == 0 -> bijective
  const int m0 = (swz >> 4) * BM;
  const int n0 = (swz & 15) * BN;

  f32x4 acc[8][4];
#pragma unroll
  for (int i = 0; i < 8; ++i)
#pragma unroll
    for (int j = 0; j < 4; ++j) acc[i][j] = (f32x4){0.f, 0.f, 0.f, 0.f};

  ushort* pA0 = lds;                  // A read slot (tile kt)
  ushort* pA1 = lds + TILE_E;         // A tile kt+1
  ushort* pA2 = lds + 2 * TILE_E;     // A stage target (tile kt+2)
  ushort* pB0 = lds + 3 * TILE_E;     // B read slot (tile kt)
  ushort* pB1 = lds + 4 * TILE_E;     // B tile kt+1

  int goffA[4], goffB[4], loff[4];
#pragma unroll
  for (int h = 0; h < 2; ++h)
#pragma unroll
    for (int rr = 0; rr < 2; ++rr) {
      const int idx = h * 2 + rr;
      const int rowb = h * 128 + rr * 64 + wave * 8;
      const int trow = rowb + (lane >> 3);
      const int sc = (lane & 7) ^ (trow & 7);
      goffA[idx] = (m0 + trow) * Kdim + sc * 8;
      goffB[idx] = (n0 + trow) * Kdim + sc * 8;
      loff[idx] = rowb * 64;
    }

#define STAGE_A(h, kcol)                                                       \
  do {                                                                         \
    gload_lds16(A + (size_t)goffA[(h)*2 + 0] + (kcol), pA2 + loff[(h)*2 + 0]); \
    gload_lds16(A + (size_t)goffA[(h)*2 + 1] + (kcol), pA2 + loff[(h)*2 + 1]); \
  } while (0)
#define STAGE_B(h, kcol)                                                       \
  do {                                                                         \
    gload_lds16(B + (size_t)goffB[(h)*2 + 0] + (kcol), pB0 + loff[(h)*2 + 0]); \
    gload_lds16(B + (size_t)goffB[(h)*2 + 1] + (kcol), pB0 + loff[(h)*2 + 1]); \
  } while (0)

  const int laneAOff = (wm * 128 + fr) * 64;
  const int laneBOff = (wn * 64 + fr) * 64;
  const int xo0 = (fq ^ (fr & 7)) * 8;
  const int xo1 = ((4 + fq) ^ (fr & 7)) * 8;

  // ---- prologue: stage A0,B0 (->slot0), A1 (->slot1), B1 (->Bslot1) ----
  {
    ushort* sv = pA2;
    pA2 = pA0; STAGE_A(0, 0); STAGE_A(1, 0);
    STAGE_B(0, 0); STAGE_B(1, 0);
    pA2 = pA1; STAGE_A(0, BK); STAGE_A(1, BK);
    { ushort* t = pB0; pB0 = pB1; STAGE_B(0, BK); STAGE_B(1, BK); pB0 = t; }
    pA2 = sv;
  }
  asm volatile("s_waitcnt vmcnt(8)" ::: "memory");   // tile0 landed; tile1 in flight
  BAR();

  bf16x8 af0[2][2], af1[2][2], bfr[4][2];
  {
    const ushort* aR0 = pA0 + laneAOff + xo0;
    const ushort* aR1 = pA0 + laneAOff + xo1;
    const ushort* bR0 = pB0 + laneBOff + xo0;
    const ushort* bR1 = pB0 + laneBOff + xo1;
#pragma unroll
    for (int ni = 0; ni < 4; ++ni) {
      bfr[ni][0] = *(const bf16x8*)(bR0 + ni * 1024);
      bfr[ni][1] = *(const bf16x8*)(bR1 + ni * 1024);
    }
#pragma unroll
    for (int m2 = 0; m2 < 2; ++m2) {
      af0[m2][0] = *(const bf16x8*)(aR0 + m2 * 1024);
      af0[m2][1] = *(const bf16x8*)(aR1 + m2 * 1024);
      af1[m2][0] = *(const bf16x8*)(aR0 + (2 + m2) * 1024);
      af1[m2][1] = *(const bf16x8*)(aR1 + (2 + m2) * 1024);
    }
  }

  for (int kt = 0; kt < NT; ++kt) {
    const int kc = (kt + 2) * BK;
    const bool stg = (kt + 2) < NT;
    const bool nxt = (kt + 1) < NT;
    const ushort* aR0 = pA0 + laneAOff + xo0;
    const ushort* aR1 = pA0 + laneAOff + xo1;
    bf16x8 af2[2][2], af3[2][2];

    // ---- ph0: read af2/af3 (rows 4-7); stage A(kt+2) h0+h1; MFMA rows 0-3; BAR ----
#pragma unroll
    for (int m2 = 0; m2 < 2; ++m2) {
      af2[m2][0] = *(const bf16x8*)(aR0 + (4 + m2) * 1024);
      af2[m2][1] = *(const bf16x8*)(aR1 + (4 + m2) * 1024);
      af3[m2][0] = *(const bf16x8*)(aR0 + (6 + m2) * 1024);
      af3[m2][1] = *(const bf16x8*)(aR1 + (6 + m2) * 1024);
    }
    if (stg) { STAGE_A(0, kc); STAGE_A(1, kc); }
    __builtin_amdgcn_s_setprio(1);
#pragma unroll
    for (int m2 = 0; m2 < 2; ++m2)
#pragma unroll
      for (int ni = 0; ni < 4; ++ni)
#pragma unroll
        for (int kk = 0; kk < 2; ++kk) {
          acc[m2][ni] = __builtin_amdgcn_mfma_f32_16x16x32_bf16(af0[m2][kk], bfr[ni][kk],
                                                                acc[m2][ni], 0, 0, 0);
          acc[2 + m2][ni] = __builtin_amdgcn_mfma_f32_16x16x32_bf16(af1[m2][kk], bfr[ni][kk],
                                                                    acc[2 + m2][ni], 0, 0, 0);
        }
    __builtin_amdgcn_s_setprio(0);
    BAR();

    // ---- ph1: stage B(kt+2) h0+h1; MFMA rows 4-7; vmcnt; next-tile reads; BAR ----
    if (stg) { STAGE_B(0, kc); STAGE_B(1, kc); }
    __builtin_amdgcn_s_setprio(1);
#pragma unroll
    for (int m2 = 0; m2 < 2; ++m2)
#pragma unroll
      for (int ni = 0; ni < 4; ++ni)
#pragma unroll
        for (int kk = 0; kk < 2; ++kk) {
          acc[4 + m2][ni] = __builtin_amdgcn_mfma_f32_16x16x32_bf16(af2[m2][kk], bfr[ni][kk],
                                                                    acc[4 + m2][ni], 0, 0, 0);
          acc[6 + m2][ni] = __builtin_amdgcn_mfma_f32_16x16x32_bf16(af3[m2][kk], bfr[ni][kk],
                                                                    acc[6 + m2][ni], 0, 0, 0);
        }
    __builtin_amdgcn_s_setprio(0);
    if (stg) asm volatile("s_waitcnt vmcnt(8)" ::: "memory");  // forces tile kt+1 landed
    else     asm volatile("s_waitcnt vmcnt(0)" ::: "memory");
    if (nxt) {
      const ushort* aN0 = pA1 + laneAOff + xo0;
      const ushort* aN1 = pA1 + laneAOff + xo1;
      const ushort* bN0 = pB1 + laneBOff + xo0;
      const ushort* bN1 = pB1 + laneBOff + xo1;
#pragma unroll
      for (int ni = 0; ni < 4; ++ni) {
        bfr[ni][0] = *(const bf16x8*)(bN0 + ni * 1024);
        bfr[ni][1] = *(const bf16x8*)(bN1 + ni * 1024);
      }
#pragma unroll
      for (int m2 = 0; m2 < 2; ++m2) {
        af0[m2][0] = *(const bf16x8*)(aN0 + m2 * 1024);
        af0[m2][1] = *(const bf16x8*)(aN1 + m2 * 1024);
        af1[m2][0] = *(const bf16x8*)(aN0 + (2 + m2) * 1024);
        af1[m2][1] = *(const bf16x8*)(aN1 + (2 + m2) * 1024);
      }
    }
    BAR();

    // rotate slots: A three-way, B swap
    { ushort* t = pA0; pA0 = pA1; pA1 = pA2; pA2 = t; }
    { ushort* t = pB0; pB0 = pB1; pB1 = t; }
  }

  const float alpha = scalep[0] * wscale2p[0];
#pragma unroll
  for (int mi = 0; mi < 8; ++mi)
#pragma unroll
    for (int ni = 0; ni < 4; ++ni) {
      const int col = n0 + wn * 64 + ni * 16 + fr;
      const int rbase = m0 + wm * 128 + mi * 16 + fq * 4;
#pragma unroll
      for (int r = 0; r < 4; ++r)
        __builtin_nontemporal_store(alpha * acc[mi][ni][r],
                                    &C[(size_t)(rbase + r) * Ndim + col]);
    }
}

// ---------------- launcher ----------------

extern "C" void kernel_launch(void* const* d_in, const int* in_sizes, int n_in,
                              void* d_out, int out_size, void* d_ws, size_t ws_size,
                              hipStream_t stream) {
  const float* x       = (const float*)d_in[0];
  const int*   w       = (const int*)d_in[1];
  const float* wscale  = (const float*)d_in[2];
  const float* wscale2 = (const float*)d_in[3];
  const float* scale   = (const float*)d_in[4];
  float* out = (float*)d_out;

  ushort* a_deq = (ushort*)d_ws;                       // 32 MB
  ushort* b_deq = a_deq + (size_t)Mdim * Kdim;         // 32 MB

  prep_kernel<<<Mdim + Ndim, 256, 0, stream>>>(x, w, wscale, scale, a_deq, b_deq);

  (void)hipFuncSetAttribute((const void*)gemm256, hipFuncAttributeMaxDynamicSharedMemorySize, 163840);
  gemm256<<<(Mdim / BM) * (Ndim / BN), 512, 163840, stream>>>(a_deq, b_deq, out, scale, wscale2);
}